// Round 8
// baseline (188.658 us; speedup 1.0000x reference)
//
#include <hip/hip_runtime.h>

// ---------------- problem constants ----------------
#define DK      768
#define M_ROWS  2048          // 8*256
#define N_ATOM  1001
#define N_BOND  301
#define N_TOT   1603          // 1001 + 2*301
#define N_PADR  1664          // 26 * 64 (padded rows of Wcat)
#define ATOM_ELEMS 2050048    // 2048*1001
#define P_ELEMS    616448     // 2048*301
#define SLAB       77056      // 256*301

typedef __attribute__((ext_vector_type(4))) float f32x4;
typedef __attribute__((ext_vector_type(8))) short bf16x8;

// exact RNE float->bf16
static __device__ __forceinline__ unsigned short f2bf(float f) {
    unsigned u = __float_as_uint(f);
    u += 0x7FFFu + ((u >> 16) & 1u);
    return (unsigned short)(u >> 16);
}

static __device__ __forceinline__ void gload_lds16(const void* g, void* l) {
    __builtin_amdgcn_global_load_lds(
        (const __attribute__((address_space(1))) unsigned*)g,
        (__attribute__((address_space(3))) unsigned*)l, 16, 0, 0);
}

// ---------------- pack: x, Wa, Wb(interleaved W1/W2) -> bf16 ----------------
__global__ __launch_bounds__(256) void pack_bf16(
    const float* __restrict__ x, const float* __restrict__ Wa,
    const float* __restrict__ Wb,
    ushort* __restrict__ xb, ushort* __restrict__ wcat)
{
    const int NX4 = (M_ROWS * DK) / 4;   // 393216
    const int NW4 = (N_PADR * DK) / 4;   // 319488
    int t = blockIdx.x * 256 + threadIdx.x;
    if (t < NX4) {
        float4 v = ((const float4*)x)[t];
        ushort4 o;
        o.x = f2bf(v.x); o.y = f2bf(v.y); o.z = f2bf(v.z); o.w = f2bf(v.w);
        ((ushort4*)xb)[t] = o;
    } else if (t < NX4 + NW4) {
        int u = t - NX4;
        int r = u / 192;                 // 192 float4 per row
        int c = (u - r * 192) * 4;
        float4 v = make_float4(0.f, 0.f, 0.f, 0.f);
        if (r < N_ATOM) {
            v = *(const float4*)(Wa + (size_t)r * DK + c);
        } else if (r < N_TOT) {
            int q = r - N_ATOM;
            v = *(const float4*)(Wb + (size_t)(q >> 1) * (2 * DK) + (q & 1) * DK + c);
        }
        ushort4 o;
        o.x = f2bf(v.x); o.y = f2bf(v.y); o.z = f2bf(v.z); o.w = f2bf(v.w);
        ((ushort4*)wcat)[u] = o;
    }
}

// ---------------- fused bf16 MFMA GEMM (global_load_lds + XOR swizzle) -------
// Identical to R4/R6/R7 (passed, known-good).
__global__ __launch_bounds__(256) void gemm_mfma(
    const ushort* __restrict__ xb, const ushort* __restrict__ wcat,
    const float* __restrict__ ba, const float* __restrict__ bb,
    float* __restrict__ atom, float* __restrict__ p1, float* __restrict__ p2)
{
    __shared__ char As[8192];   // 64 rows x 128B
    __shared__ char Bs[8192];

    const int tid  = threadIdx.x;
    const int lane = tid & 63;
    const int wid  = tid >> 6;     // 4 waves: 2x2
    const int wr   = wid >> 1;
    const int wc   = wid & 1;
    const int m0   = blockIdx.y * 64;
    const int n0   = blockIdx.x * 64;

    f32x4 acc[2][2] = {};

    const int lrow = lane >> 3;                 // 0..7
    const int lcx  = ((lane & 7) ^ lrow) * 8;   // inverse-swizzled k-chunk (elems)

    const ushort* Ag = xb   + (size_t)m0 * DK;
    const ushort* Bg = wcat + (size_t)n0 * DK;

    for (int k0 = 0; k0 < DK; k0 += 64) {
        __syncthreads();   // previous compute done before overwrite
        #pragma unroll
        for (int t = 0; t < 2; ++t) {
            const int s = wid + 4 * t;          // segment 0..7 (1KB each)
            gload_lds16(Ag + (size_t)(s * 8 + lrow) * DK + k0 + lcx, As + s * 1024);
            gload_lds16(Bg + (size_t)(s * 8 + lrow) * DK + k0 + lcx, Bs + s * 1024);
        }
        __syncthreads();   // compiler drains vmcnt(0) before s_barrier
        #pragma unroll
        for (int ks = 0; ks < 2; ++ks) {
            const int kc = ks * 4 + (lane >> 4);
            bf16x8 af[2], bfr[2];
            #pragma unroll
            for (int i = 0; i < 2; ++i) {
                int ra = wr * 32 + i * 16 + (lane & 15);
                af[i]  = *(const bf16x8*)(As + ra * 128 + ((kc ^ (ra & 7)) << 4));
                int rb = wc * 32 + i * 16 + (lane & 15);
                bfr[i] = *(const bf16x8*)(Bs + rb * 128 + ((kc ^ (rb & 7)) << 4));
            }
            #pragma unroll
            for (int i = 0; i < 2; ++i)
                #pragma unroll
                for (int j = 0; j < 2; ++j)
                    acc[i][j] = __builtin_amdgcn_mfma_f32_16x16x32_bf16(
                        af[i], bfr[j], acc[i][j], 0, 0, 0);
        }
    }

    // epilogue: D col = lane&15, row = (lane>>4)*4 + reg  [verified r2/r4/r6/r7]
    #pragma unroll
    for (int i = 0; i < 2; ++i) {
        #pragma unroll
        for (int j = 0; j < 2; ++j) {
            #pragma unroll
            for (int reg = 0; reg < 4; ++reg) {
                int m = m0 + wr * 32 + i * 16 + (lane >> 4) * 4 + reg;
                int n = n0 + wc * 32 + j * 16 + (lane & 15);
                float v = acc[i][j][reg];
                if (n < N_ATOM) {
                    atom[(size_t)m * N_ATOM + n] = v + ba[n];
                } else if (n < N_TOT) {
                    int q = n - N_ATOM, rr = q >> 1;
                    if (q & 1) p2[(size_t)m * N_BOND + rr] = v + bb[rr];
                    else       p1[(size_t)m * N_BOND + rr] = v;
                }
            }
        }
    }
}

// ---------------- bond broadcast, tiled + NT stores ----------------
// Identical structure to R7 (tiled LDS, reads collapsed); single change:
// store is nontemporal (R6 vs R4 A/B showed NT = -32 us on the flat form).
__global__ __launch_bounds__(256) void bond_bcast(
    const float* __restrict__ p1, const float* __restrict__ p2,
    float* __restrict__ out)
{
    __shared__ float p1s[32 * N_BOND];   // 9632 floats
    __shared__ float p2s[16 * N_BOND];   // 4816 floats
    const int blk = blockIdx.x;          // 1024 = 8b x 8it x 16jt
    const int b   = blk >> 7;
    const int it  = (blk >> 4) & 7;
    const int jt  = blk & 15;
    const int tid = threadIdx.x;

    const f32x4* p1g = (const f32x4*)(p1 + (size_t)(b * 256 + it * 32) * N_BOND);
    const f32x4* p2g = (const f32x4*)(p2 + (size_t)(b * 256 + jt * 16) * N_BOND);
    for (int k = tid; k < 2408; k += 256) ((f32x4*)p1s)[k] = p1g[k];
    for (int k = tid; k < 1204; k += 256) ((f32x4*)p2s)[k] = p2g[k];
    __syncthreads();

    float* dst = out + (size_t)(b * 256 + it * 32) * SLAB + (size_t)(jt * 16) * N_BOND;
    for (int i = 0; i < 32; ++i) {
        const float* p1r = p1s + i * N_BOND;
        float* o = dst + (size_t)i * SLAB;
        int n = tid;                       // e mod 301 (tid < 301)
        #pragma unroll
        for (int k = 0; k < 19; ++k) {
            int e = tid + k * 256;
            if (k < 18 || e < 4816)
                __builtin_nontemporal_store(p1r[n] + p2s[e], &o[e]);
            n += 256; if (n >= N_BOND) n -= N_BOND;
        }
    }
}

// ---------------- launch ----------------
extern "C" void kernel_launch(void* const* d_in, const int* in_sizes, int n_in,
                              void* d_out, int out_size, void* d_ws, size_t ws_size,
                              hipStream_t stream) {
    const float* x  = (const float*)d_in[0];   // (8,256,768)
    const float* Wa = (const float*)d_in[1];   // (1001,768)
    const float* ba = (const float*)d_in[2];   // (1001,)
    const float* Wb = (const float*)d_in[3];   // (301,1536)
    const float* bb = (const float*)d_in[4];   // (301,)

    float* out  = (float*)d_out;
    float* atom = out;                 // 2,050,048 floats
    float* bond = out + ATOM_ELEMS;    // 157,810,688 floats

    // ws layout (16B-aligned sections)
    ushort* xb   = (ushort*)d_ws;                        // 2048*768 bf16
    ushort* wcat = xb + (size_t)M_ROWS * DK;             // 1664*768 bf16
    float*  p1   = (float*)(wcat + (size_t)N_PADR * DK); // 2048*301 f32
    float*  p2   = p1 + P_ELEMS;                         // 2048*301 f32

    pack_bf16<<<dim3(2784), dim3(256), 0, stream>>>(x, Wa, Wb, xb, wcat);

    gemm_mfma<<<dim3(N_PADR / 64, M_ROWS / 64), dim3(256), 0, stream>>>(
        xb, wcat, ba, bb, atom, p1, p2);

    bond_bcast<<<dim3(1024), dim3(256), 0, stream>>>(p1, p2, bond);
}

// Round 9
// 153.832 us; speedup vs baseline: 1.2264x; 1.2264x over previous
//
#include <hip/hip_runtime.h>

// ---------------- problem constants ----------------
#define DK      768
#define M_ROWS  2048          // 8*256
#define N_ATOM  1001
#define N_BOND  301
#define N_TOT   1603          // 1001 + 2*301
#define N_PADR  1664          // 26 * 64 (padded rows of Wcat)
#define ATOM_ELEMS 2050048    // 2048*1001
#define P_ELEMS    616448     // 2048*301
#define SLAB       77056      // 256*301

typedef __attribute__((ext_vector_type(4))) float f32x4;
typedef __attribute__((ext_vector_type(8))) short bf16x8;

// exact RNE float->bf16
static __device__ __forceinline__ unsigned short f2bf(float f) {
    unsigned u = __float_as_uint(f);
    u += 0x7FFFu + ((u >> 16) & 1u);
    return (unsigned short)(u >> 16);
}

static __device__ __forceinline__ void gload_lds16(const void* g, void* l) {
    __builtin_amdgcn_global_load_lds(
        (const __attribute__((address_space(1))) unsigned*)g,
        (__attribute__((address_space(3))) unsigned*)l, 16, 0, 0);
}

// ---------------- pack: x, Wa, Wb(interleaved W1/W2) -> bf16 ----------------
__global__ __launch_bounds__(256) void pack_bf16(
    const float* __restrict__ x, const float* __restrict__ Wa,
    const float* __restrict__ Wb,
    ushort* __restrict__ xb, ushort* __restrict__ wcat)
{
    const int NX4 = (M_ROWS * DK) / 4;   // 393216
    const int NW4 = (N_PADR * DK) / 4;   // 319488
    int t = blockIdx.x * 256 + threadIdx.x;
    if (t < NX4) {
        float4 v = ((const float4*)x)[t];
        ushort4 o;
        o.x = f2bf(v.x); o.y = f2bf(v.y); o.z = f2bf(v.z); o.w = f2bf(v.w);
        ((ushort4*)xb)[t] = o;
    } else if (t < NX4 + NW4) {
        int u = t - NX4;
        int r = u / 192;                 // 192 float4 per row
        int c = (u - r * 192) * 4;
        float4 v = make_float4(0.f, 0.f, 0.f, 0.f);
        if (r < N_ATOM) {
            v = *(const float4*)(Wa + (size_t)r * DK + c);
        } else if (r < N_TOT) {
            int q = r - N_ATOM;
            v = *(const float4*)(Wb + (size_t)(q >> 1) * (2 * DK) + (q & 1) * DK + c);
        }
        ushort4 o;
        o.x = f2bf(v.x); o.y = f2bf(v.y); o.z = f2bf(v.z); o.w = f2bf(v.w);
        ((ushort4*)wcat)[u] = o;
    }
}

// ---------------- fused bf16 MFMA GEMM (global_load_lds + XOR swizzle) -------
// Identical to R4/R6/R7/R8 (passed, known-good).
__global__ __launch_bounds__(256) void gemm_mfma(
    const ushort* __restrict__ xb, const ushort* __restrict__ wcat,
    const float* __restrict__ ba, const float* __restrict__ bb,
    float* __restrict__ atom, float* __restrict__ p1, float* __restrict__ p2)
{
    __shared__ char As[8192];   // 64 rows x 128B
    __shared__ char Bs[8192];

    const int tid  = threadIdx.x;
    const int lane = tid & 63;
    const int wid  = tid >> 6;     // 4 waves: 2x2
    const int wr   = wid >> 1;
    const int wc   = wid & 1;
    const int m0   = blockIdx.y * 64;
    const int n0   = blockIdx.x * 64;

    f32x4 acc[2][2] = {};

    const int lrow = lane >> 3;                 // 0..7
    const int lcx  = ((lane & 7) ^ lrow) * 8;   // inverse-swizzled k-chunk (elems)

    const ushort* Ag = xb   + (size_t)m0 * DK;
    const ushort* Bg = wcat + (size_t)n0 * DK;

    for (int k0 = 0; k0 < DK; k0 += 64) {
        __syncthreads();   // previous compute done before overwrite
        #pragma unroll
        for (int t = 0; t < 2; ++t) {
            const int s = wid + 4 * t;          // segment 0..7 (1KB each)
            gload_lds16(Ag + (size_t)(s * 8 + lrow) * DK + k0 + lcx, As + s * 1024);
            gload_lds16(Bg + (size_t)(s * 8 + lrow) * DK + k0 + lcx, Bs + s * 1024);
        }
        __syncthreads();   // compiler drains vmcnt(0) before s_barrier
        #pragma unroll
        for (int ks = 0; ks < 2; ++ks) {
            const int kc = ks * 4 + (lane >> 4);
            bf16x8 af[2], bfr[2];
            #pragma unroll
            for (int i = 0; i < 2; ++i) {
                int ra = wr * 32 + i * 16 + (lane & 15);
                af[i]  = *(const bf16x8*)(As + ra * 128 + ((kc ^ (ra & 7)) << 4));
                int rb = wc * 32 + i * 16 + (lane & 15);
                bfr[i] = *(const bf16x8*)(Bs + rb * 128 + ((kc ^ (rb & 7)) << 4));
            }
            #pragma unroll
            for (int i = 0; i < 2; ++i)
                #pragma unroll
                for (int j = 0; j < 2; ++j)
                    acc[i][j] = __builtin_amdgcn_mfma_f32_16x16x32_bf16(
                        af[i], bfr[j], acc[i][j], 0, 0, 0);
        }
    }

    // epilogue: D col = lane&15, row = (lane>>4)*4 + reg  [verified r2/r4/r6/r7]
    #pragma unroll
    for (int i = 0; i < 2; ++i) {
        #pragma unroll
        for (int j = 0; j < 2; ++j) {
            #pragma unroll
            for (int reg = 0; reg < 4; ++reg) {
                int m = m0 + wr * 32 + i * 16 + (lane >> 4) * 4 + reg;
                int n = n0 + wc * 32 + j * 16 + (lane & 15);
                float v = acc[i][j][reg];
                if (n < N_ATOM) {
                    atom[(size_t)m * N_ATOM + n] = v + ba[n];
                } else if (n < N_TOT) {
                    int q = n - N_ATOM, rr = q >> 1;
                    if (q & 1) p2[(size_t)m * N_BOND + rr] = v + bb[rr];
                    else       p1[(size_t)m * N_BOND + rr] = v;
                }
            }
        }
    }
}

// ---------------- bond broadcast: tiled LDS reads + NT float4 stores --------
// Block (b,it,jt): stage p1 tile (32 rows, swizzled idx n+(n>>3)) and p2 tile
// (16 rows, flat) in LDS. Per-i output row-slab = 16*301 = 4816 floats = 1204 f4;
// flat f4 index f: p2 value = p2s4[f] (hoisted over i), p1 gathers at
// n..n+3 (mod 301), n advanced incrementally (+121 per 256 f4) -> no divides.
// Stores: nontemporal dwordx4 (R4-proven fast path: full 64B lines, no L2 churn).
__global__ __launch_bounds__(256) void bond_bcast(
    const float* __restrict__ p1, const float* __restrict__ p2,
    float* __restrict__ out)
{
    __shared__ float p1s[32 * 344];      // swizzled rows (max idx 337)
    __shared__ float p2s[16 * N_BOND];   // 4816 floats flat
    const int blk = blockIdx.x;          // 1024 = 8b x 8it x 16jt
    const int b   = blk >> 7;
    const int it  = (blk >> 4) & 7;
    const int jt  = blk & 15;
    const int tid = threadIdx.x;

    const float* p1g = p1 + (size_t)(b * 256 + it * 32) * N_BOND;
    for (int t = tid; t < 32 * N_BOND; t += 256) {
        int r = t / N_BOND, n = t - r * N_BOND;
        p1s[r * 344 + n + (n >> 3)] = p1g[t];
    }
    const f32x4* p2g = (const f32x4*)(p2 + (size_t)(b * 256 + jt * 16) * N_BOND);
    for (int k = tid; k < 1204; k += 256) ((f32x4*)p2s)[k] = p2g[k];
    __syncthreads();

    float* dst = out + (size_t)(b * 256 + it * 32) * SLAB + (size_t)(jt * 16) * N_BOND;

    int n = (4 * tid) % 301;
    #pragma unroll
    for (int k = 0; k < 5; ++k) {
        const int f = tid + k * 256;
        if (f < 1204) {
            const f32x4 pv = ((const f32x4*)p2s)[f];
            int n1 = n + 1; if (n1 >= 301) n1 -= 301;
            int n2 = n + 2; if (n2 >= 301) n2 -= 301;
            int n3 = n + 3; if (n3 >= 301) n3 -= 301;
            const int g0 = n + (n >> 3),   g1 = n1 + (n1 >> 3);
            const int g2 = n2 + (n2 >> 3), g3 = n3 + (n3 >> 3);
            for (int i = 0; i < 32; ++i) {
                const float* p1r = p1s + i * 344;
                f32x4 v = pv;
                v.x += p1r[g0]; v.y += p1r[g1]; v.z += p1r[g2]; v.w += p1r[g3];
                __builtin_nontemporal_store(v, (f32x4*)(dst + (size_t)i * SLAB) + f);
            }
        }
        n += 121; if (n >= 301) n -= 301;
    }
}

// ---------------- launch ----------------
extern "C" void kernel_launch(void* const* d_in, const int* in_sizes, int n_in,
                              void* d_out, int out_size, void* d_ws, size_t ws_size,
                              hipStream_t stream) {
    const float* x  = (const float*)d_in[0];   // (8,256,768)
    const float* Wa = (const float*)d_in[1];   // (1001,768)
    const float* ba = (const float*)d_in[2];   // (1001,)
    const float* Wb = (const float*)d_in[3];   // (301,1536)
    const float* bb = (const float*)d_in[4];   // (301,)

    float* out  = (float*)d_out;
    float* atom = out;                 // 2,050,048 floats
    float* bond = out + ATOM_ELEMS;    // 157,810,688 floats

    // ws layout (16B-aligned sections)
    ushort* xb   = (ushort*)d_ws;                        // 2048*768 bf16
    ushort* wcat = xb + (size_t)M_ROWS * DK;             // 1664*768 bf16
    float*  p1   = (float*)(wcat + (size_t)N_PADR * DK); // 2048*301 f32
    float*  p2   = p1 + P_ELEMS;                         // 2048*301 f32

    pack_bf16<<<dim3(2784), dim3(256), 0, stream>>>(x, Wa, Wb, xb, wcat);

    gemm_mfma<<<dim3(N_PADR / 64, M_ROWS / 64), dim3(256), 0, stream>>>(
        xb, wcat, ba, bb, atom, p1, p2);

    bond_bcast<<<dim3(1024), dim3(256), 0, stream>>>(p1, p2, bond);
}